// Round 5
// baseline (410.104 us; speedup 1.0000x reference)
//
#include <hip/hip_runtime.h>

#define D_EMB 768
#define NH 12
#define DK 64
#define NB 2
#define SS 4096
#define E3 (3*D_EMB)   // 2304
#define MM (NB*SS)     // 8192

typedef unsigned short u16;
typedef __attribute__((ext_vector_type(8))) __bf16 bf16x8;
typedef __attribute__((ext_vector_type(4))) float f32x4;
typedef __attribute__((ext_vector_type(4))) unsigned int u32x4;

static __device__ __forceinline__ u16 f2bf(float f) {
  unsigned u = __builtin_bit_cast(unsigned, f);
  u += 0x7fffu + ((u >> 16) & 1u);          // round-to-nearest-even
  return (u16)(u >> 16);
}
static __device__ __forceinline__ f32x4 mfma16(bf16x8 a, bf16x8 b, f32x4 c) {
  return __builtin_amdgcn_mfma_f32_16x16x32_bf16(a, b, c, 0, 0, 0);
}
static __device__ __forceinline__ float exp2_fast(float x) {
#if __has_builtin(__builtin_amdgcn_exp2f)
  return __builtin_amdgcn_exp2f(x);
#else
  return __builtin_exp2f(x);
#endif
}
static __device__ __forceinline__ float rcp_fast(float x) {
#if __has_builtin(__builtin_amdgcn_rcpf)
  return __builtin_amdgcn_rcpf(x);
#else
  return 1.f / x;
#endif
}
static __device__ __forceinline__ void gload_lds16(const u16* g, u16* l) {
  __builtin_amdgcn_global_load_lds((const __attribute__((address_space(1))) void*)g,
                                   (__attribute__((address_space(3))) void*)l, 16, 0, 0);
}

// ---------------- cast fp32 -> bf16, elementwise ----------------
__global__ __launch_bounds__(256) void cast_kernel(const float* __restrict__ in,
                                                   u16* __restrict__ out, int n) {
  int i = (blockIdx.x * 256 + threadIdx.x) * 4;
  if (i + 3 < n) {
    float4 v = *(const float4*)(in + i);
    out[i + 0] = f2bf(v.x);
    out[i + 1] = f2bf(v.y);
    out[i + 2] = f2bf(v.z);
    out[i + 3] = f2bf(v.w);
  }
}

// -------- transpose + cast all four weights (z selects): WT[n][k] = W[k][n] * scale --------
__global__ __launch_bounds__(256) void transpose_cast_all(const float* __restrict__ Wq,
                                                          const float* __restrict__ Wk,
                                                          const float* __restrict__ Wv,
                                                          const float* __restrict__ Wo,
                                                          u16* __restrict__ WTqkv,
                                                          u16* __restrict__ WoT, float qscale) {
  __shared__ float tile[32][33];
  int z = blockIdx.z;
  const float* W = (z == 0) ? Wq : (z == 1) ? Wk : (z == 2) ? Wv : Wo;
  u16* WT = (z < 3) ? WTqkv + (size_t)z * D_EMB * D_EMB : WoT;
  float scale = (z == 0) ? qscale : 1.0f;
  int kb = blockIdx.y * 32, nb = blockIdx.x * 32;
  int tx = threadIdx.x, ty = threadIdx.y;
#pragma unroll
  for (int i = 0; i < 4; i++)
    tile[ty + i * 8][tx] = W[(size_t)(kb + ty + i * 8) * D_EMB + nb + tx];
  __syncthreads();
#pragma unroll
  for (int i = 0; i < 4; i++)
    WT[(size_t)(nb + ty + i * 8) * D_EMB + kb + tx] = f2bf(tile[tx][ty + i * 8] * scale);
}

// -------- transpose V (bf16), pi-permuted columns within each 64-block --------
__global__ __launch_bounds__(256) void transpose_v(const u16* __restrict__ QKV,
                                                   u16* __restrict__ VT) {
  __shared__ u16 tile[32][33];
  int bh = blockIdx.z;
  int b = bh / NH, h = bh % NH;
  int sb = blockIdx.x * 32, db = blockIdx.y * 32;
  int tx = threadIdx.x, ty = threadIdx.y;
  const u16* src = QKV + (size_t)(b * SS) * E3 + 2 * D_EMB + h * DK;
  u16* dst = VT + (size_t)bh * DK * SS;
#pragma unroll
  for (int i = 0; i < 4; i++)
    tile[ty + i * 8][tx] = src[(size_t)(sb + ty + i * 8) * E3 + db + tx];
  __syncthreads();
  int s = sb + tx;
  int k6 = s & 63;
  int p = (s & ~63) | (k6 & 0x23) | ((k6 & 0x0C) << 1) | ((k6 & 0x10) >> 2);
#pragma unroll
  for (int i = 0; i < 4; i++)
    dst[(size_t)(db + ty + i * 8) * SS + p] = tile[tx][ty + i * 8];
}

// ---------------- bf16 GEMM, B given transposed ----------------
template <int OUTF32>
__global__ __launch_bounds__(256) void gemm_bt(const u16* __restrict__ A,
                                               const u16* __restrict__ Bt,
                                               void* __restrict__ Cout,
                                               int M, int N, int K, float scale) {
  __shared__ __align__(16) u16 As[128 * 32];
  __shared__ __align__(16) u16 Bs[128 * 32];
  int tid = threadIdx.x;
  int wave = tid >> 6, lane = tid & 63;
  int g = lane >> 4, nIdx = lane & 15;
  int m0 = blockIdx.y * 128, n0 = blockIdx.x * 128;
  int wm = (wave >> 1) * 64, wn = (wave & 1) * 64;

  f32x4 acc[4][4] = {};

  int row = tid >> 2, co = (tid & 3) * 8;
  int row2 = row + 64;

  for (int k0 = 0; k0 < K; k0 += 32) {
    __syncthreads();
    gload_lds16(A  + (size_t)(m0 + row)  * K + k0 + co, As + row  * 32 + co);
    gload_lds16(Bt + (size_t)(n0 + row)  * K + k0 + co, Bs + row  * 32 + co);
    gload_lds16(A  + (size_t)(m0 + row2) * K + k0 + co, As + row2 * 32 + co);
    gload_lds16(Bt + (size_t)(n0 + row2) * K + k0 + co, Bs + row2 * 32 + co);
    __syncthreads();

    bf16x8 af[4], bfr[4];
#pragma unroll
    for (int i = 0; i < 4; i++)
      af[i] = *(const bf16x8*)(As + (wm + i * 16 + nIdx) * 32 + g * 8);
#pragma unroll
    for (int j = 0; j < 4; j++)
      bfr[j] = *(const bf16x8*)(Bs + (wn + j * 16 + nIdx) * 32 + g * 8);
#pragma unroll
    for (int i = 0; i < 4; i++)
#pragma unroll
      for (int j = 0; j < 4; j++)
        acc[i][j] = mfma16(af[i], bfr[j], acc[i][j]);
  }

#pragma unroll
  for (int i = 0; i < 4; i++)
#pragma unroll
    for (int j = 0; j < 4; j++)
#pragma unroll
      for (int r = 0; r < 4; r++) {
        int rr = m0 + wm + i * 16 + g * 4 + r;
        int cc = n0 + wn + j * 16 + nIdx;
        float v = acc[i][j][r] * scale;
        if (OUTF32)
          ((float*)Cout)[(size_t)rr * N + cc] = v;
        else
          ((u16*)Cout)[(size_t)rr * N + cc] = f2bf(v);
      }
}

// ---------------- flash attention v5 ----------------
// v4 structure (4 waves = q-half x kv-stream, q=64/wave, stream merge via LDS)
// with v3-VERIFIED padded manual staging (no global_load_lds, no swizzle).
// Q pre-scaled by 0.125*log2(e); pi-permuted V makes P C-layout == PV B-frag.
__global__ __launch_bounds__(256, 3) void flash(const u16* __restrict__ QKV,
                                                const u16* __restrict__ VT,
                                                u16* __restrict__ O) {
  // per stream: K tile 64x72 + V tile 64x72 (u16). 2 streams = 18432 u16 = 36864 B.
  // epilogue merge dump (34816 B) reuses this space.
  __shared__ __align__(16) u16 smem[18432];

  int b = blockIdx.z, h = blockIdx.y;
  int q0 = blockIdx.x * 128;
  int tid = threadIdx.x, w = tid >> 6, l = tid & 63;
  int g = l >> 4, n = l & 15;
  int qh = w & 1, st = w >> 1;

  const u16* VTb = VT + (size_t)(b * NH + h) * DK * SS;
  u16* pKs = smem + st * 9216;
  u16* pVs = pKs + 4608;

  // --- Q fragments: 64 rows for this wave ---
  const u16* Qbase = QKV + (size_t)(b * SS + q0 + qh * 64) * E3 + h * DK;
  bf16x8 qf[4][2];
#pragma unroll
  for (int qg = 0; qg < 4; qg++)
#pragma unroll
    for (int hf = 0; hf < 2; hf++)
      qf[qg][hf] = *(const bf16x8*)(Qbase + (size_t)(qg * 16 + n) * E3 + hf * 32 + g * 8);

  f32x4 o_acc[4][4] = {};
  float lsum[4] = {0.f, 0.f, 0.f, 0.f};
  u32x4 onev = {0x3F803F80u, 0x3F803F80u, 0x3F803F80u, 0x3F803F80u};
  bf16x8 aone = __builtin_bit_cast(bf16x8, onev);

  // --- staging: even waves stage K of their stream, odd waves stage V ---
  int rL = l >> 3, cL = l & 7;
  const u16* g0;
  size_t rstep, tstep;
  u16* sW;
  if ((w & 1) == 0) {
    g0 = QKV + ((size_t)(b * SS) + st * 2048 + rL) * E3 + D_EMB + h * DK + cL * 8;
    rstep = (size_t)8 * E3;
    tstep = (size_t)64 * E3;
    sW = pKs + rL * 72 + cL * 8;
  } else {
    g0 = VTb + (size_t)rL * SS + st * 2048 + cL * 8;
    rstep = (size_t)8 * SS;
    tstep = 64;
    sW = pVs + rL * 72 + cL * 8;
  }

  uint4 pf[8];
#pragma unroll
  for (int i = 0; i < 8; i++)
    pf[i] = *(const uint4*)(g0 + i * rstep);

  for (int kt = 0; kt < 32; kt++) {
    __syncthreads();                          // previous tile's reads done
#pragma unroll
    for (int i = 0; i < 8; i++)
      *(uint4*)(sW + i * 576) = pf[i];        // row 8i+rL (72-stride), chunk cL
    __syncthreads();                          // writes visible

    if (kt < 31) {                            // prefetch next tile into regs
      const u16* gn = g0 + (size_t)(kt + 1) * tstep;
#pragma unroll
      for (int i = 0; i < 8; i++)
        pf[i] = *(const uint4*)(gn + i * rstep);
    }

#pragma unroll
    for (int s = 0; s < 2; s++) {             // 32-kv sub-round
      bf16x8 kf[2][2];
#pragma unroll
      for (int jj = 0; jj < 2; jj++)
#pragma unroll
        for (int hf = 0; hf < 2; hf++)
          kf[jj][hf] = *(const bf16x8*)(pKs + ((2 * s + jj) * 16 + n) * 72 + hf * 32 + g * 8);

#pragma unroll
      for (int p = 0; p < 2; p++) {           // q-group pair
        f32x4 C[2][2];
#pragma unroll
        for (int q2 = 0; q2 < 2; q2++) {
          int qg = 2 * p + q2;
#pragma unroll
          for (int jj = 0; jj < 2; jj++) {
            f32x4 t = {};
            t = mfma16(kf[jj][0], qf[qg][0], t);
            t = mfma16(kf[jj][1], qf[qg][1], t);
            C[q2][jj] = t;
          }
        }
        u32x4 Bw[2];
#pragma unroll
        for (int q2 = 0; q2 < 2; q2++)
#pragma unroll
          for (int jj = 0; jj < 2; jj++) {
            float p0 = exp2_fast(C[q2][jj][0]);
            float p1 = exp2_fast(C[q2][jj][1]);
            float p2 = exp2_fast(C[q2][jj][2]);
            float p3 = exp2_fast(C[q2][jj][3]);
            Bw[q2][jj * 2] = __builtin_amdgcn_perm(__builtin_bit_cast(unsigned, p1),
                                                   __builtin_bit_cast(unsigned, p0), 0x07060302u);
            Bw[q2][jj * 2 + 1] = __builtin_amdgcn_perm(__builtin_bit_cast(unsigned, p3),
                                                       __builtin_bit_cast(unsigned, p2), 0x07060302u);
          }
#pragma unroll
        for (int q2 = 0; q2 < 2; q2++) {
          f32x4 z = {};
          z = mfma16(aone, __builtin_bit_cast(bf16x8, Bw[q2]), z);
          lsum[2 * p + q2] += z[0];
        }
#pragma unroll
        for (int dt = 0; dt < 4; dt++) {
          bf16x8 vf = *(const bf16x8*)(pVs + (dt * 16 + n) * 72 + s * 32 + g * 8);
#pragma unroll
          for (int q2 = 0; q2 < 2; q2++)
            o_acc[2 * p + q2][dt] = mfma16(vf, __builtin_bit_cast(bf16x8, Bw[q2]),
                                           o_acc[2 * p + q2][dt]);
        }
      }
    }
  }

  __syncthreads();                            // all reads done before dump reuses smem

  // --- cross-wave merge: stream B dumps (O,l), stream A adds & writes ---
  float* dumpF = (float*)smem;
  if (w >= 2) {
    float* dst = dumpF + ((size_t)((w - 2) * 64 + l)) * 68;
#pragma unroll
    for (int qg = 0; qg < 4; qg++)
#pragma unroll
      for (int dt = 0; dt < 4; dt++)
        *(f32x4*)(dst + (qg * 4 + dt) * 4) = o_acc[qg][dt];
    f32x4 lv = {lsum[0], lsum[1], lsum[2], lsum[3]};
    *(f32x4*)(dst + 64) = lv;
  }
  __syncthreads();
  if (w < 2) {
    float* src = dumpF + ((size_t)(w * 64 + l)) * 68;
#pragma unroll
    for (int qg = 0; qg < 4; qg++)
#pragma unroll
      for (int dt = 0; dt < 4; dt++)
        o_acc[qg][dt] += *(f32x4*)(src + (qg * 4 + dt) * 4);
    f32x4 lv = *(f32x4*)(src + 64);
#pragma unroll
    for (int qg = 0; qg < 4; qg++) {
      float rl = rcp_fast(lsum[qg] + lv[qg]);
      u16* Obp = O + (size_t)(b * SS + q0 + w * 64 + qg * 16 + n) * D_EMB + h * DK;
#pragma unroll
      for (int dt = 0; dt < 4; dt++) {
        uint2 pk;
        pk.x = (unsigned)f2bf(o_acc[qg][dt][0] * rl) |
               ((unsigned)f2bf(o_acc[qg][dt][1] * rl) << 16);
        pk.y = (unsigned)f2bf(o_acc[qg][dt][2] * rl) |
               ((unsigned)f2bf(o_acc[qg][dt][3] * rl) << 16);
        *(uint2*)(Obp + dt * 16 + g * 4) = pk;
      }
    }
  }
}

extern "C" void kernel_launch(void* const* d_in, const int* in_sizes, int n_in,
                              void* d_out, int out_size, void* d_ws, size_t ws_size,
                              hipStream_t stream) {
  const float* X  = (const float*)d_in[0];
  const float* Wq = (const float*)d_in[1];
  const float* Wk = (const float*)d_in[2];
  const float* Wv = (const float*)d_in[3];
  const float* Wo = (const float*)d_in[4];
  float* out = (float*)d_out;

  u16* Xb    = (u16*)d_ws;                         // MM*D_EMB
  u16* WTqkv = Xb + (size_t)MM * D_EMB;            // E3*D_EMB
  u16* WoT   = WTqkv + (size_t)E3 * D_EMB;         // D_EMB*D_EMB
  u16* QKV   = WoT + (size_t)D_EMB * D_EMB;        // MM*E3
  u16* VT    = QKV + (size_t)MM * E3;              // NB*NH*DK*SS
  u16* Ob    = VT + (size_t)NB * NH * DK * SS;     // MM*D_EMB

  dim3 tb(32, 8);
  cast_kernel<<<(MM * D_EMB) / 1024, 256, 0, stream>>>(X, Xb, MM * D_EMB);
  transpose_cast_all<<<dim3(24, 24, 4), tb, 0, stream>>>(Wq, Wk, Wv, Wo, WTqkv, WoT,
                                                         0.125f * 1.4426950408889634f);
  gemm_bt<0><<<dim3(E3 / 128, MM / 128), 256, 0, stream>>>(Xb, WTqkv, (void*)QKV,
                                                           MM, E3, D_EMB, 1.0f);
  transpose_v<<<dim3(SS / 32, 2, NB * NH), tb, 0, stream>>>(QKV, VT);
  flash<<<dim3(SS / 128, NH, NB), 256, 0, stream>>>(QKV, VT, Ob);
  gemm_bt<1><<<dim3(D_EMB / 128, MM / 128), 256, 0, stream>>>(Ob, WoT, (void*)out,
                                                              MM, D_EMB, D_EMB, 1.0f);
}

// Round 6
// 409.291 us; speedup vs baseline: 1.0020x; 1.0020x over previous
//
#include <hip/hip_runtime.h>

#define D_EMB 768
#define NH 12
#define DK 64
#define NB 2
#define SS 4096
#define E3 (3*D_EMB)   // 2304
#define MM (NB*SS)     // 8192

typedef unsigned short u16;
typedef __attribute__((ext_vector_type(8))) __bf16 bf16x8;
typedef __attribute__((ext_vector_type(4))) float f32x4;
typedef __attribute__((ext_vector_type(4))) unsigned int u32x4;

static __device__ __forceinline__ u16 f2bf(float f) {
  unsigned u = __builtin_bit_cast(unsigned, f);
  u += 0x7fffu + ((u >> 16) & 1u);          // round-to-nearest-even
  return (u16)(u >> 16);
}
static __device__ __forceinline__ f32x4 mfma16(bf16x8 a, bf16x8 b, f32x4 c) {
  return __builtin_amdgcn_mfma_f32_16x16x32_bf16(a, b, c, 0, 0, 0);
}
static __device__ __forceinline__ float exp2_fast(float x) {
#if __has_builtin(__builtin_amdgcn_exp2f)
  return __builtin_amdgcn_exp2f(x);
#else
  return __builtin_exp2f(x);
#endif
}
static __device__ __forceinline__ float rcp_fast(float x) {
#if __has_builtin(__builtin_amdgcn_rcpf)
  return __builtin_amdgcn_rcpf(x);
#else
  return 1.f / x;
#endif
}
static __device__ __forceinline__ void gload_lds16(const u16* g, u16* l) {
  __builtin_amdgcn_global_load_lds((const __attribute__((address_space(1))) void*)g,
                                   (__attribute__((address_space(3))) void*)l, 16, 0, 0);
}

// ---------------- cast fp32 -> bf16, elementwise ----------------
__global__ __launch_bounds__(256) void cast_kernel(const float* __restrict__ in,
                                                   u16* __restrict__ out, int n) {
  int i = (blockIdx.x * 256 + threadIdx.x) * 4;
  if (i + 3 < n) {
    float4 v = *(const float4*)(in + i);
    out[i + 0] = f2bf(v.x);
    out[i + 1] = f2bf(v.y);
    out[i + 2] = f2bf(v.z);
    out[i + 3] = f2bf(v.w);
  }
}

// -------- transpose + cast all four weights (z selects): WT[n][k] = W[k][n] * scale --------
__global__ __launch_bounds__(256) void transpose_cast_all(const float* __restrict__ Wq,
                                                          const float* __restrict__ Wk,
                                                          const float* __restrict__ Wv,
                                                          const float* __restrict__ Wo,
                                                          u16* __restrict__ WTqkv,
                                                          u16* __restrict__ WoT, float qscale) {
  __shared__ float tile[32][33];
  int z = blockIdx.z;
  const float* W = (z == 0) ? Wq : (z == 1) ? Wk : (z == 2) ? Wv : Wo;
  u16* WT = (z < 3) ? WTqkv + (size_t)z * D_EMB * D_EMB : WoT;
  float scale = (z == 0) ? qscale : 1.0f;
  int kb = blockIdx.y * 32, nb = blockIdx.x * 32;
  int tx = threadIdx.x, ty = threadIdx.y;
#pragma unroll
  for (int i = 0; i < 4; i++)
    tile[ty + i * 8][tx] = W[(size_t)(kb + ty + i * 8) * D_EMB + nb + tx];
  __syncthreads();
#pragma unroll
  for (int i = 0; i < 4; i++)
    WT[(size_t)(nb + ty + i * 8) * D_EMB + kb + tx] = f2bf(tile[tx][ty + i * 8] * scale);
}

// -------- transpose V (bf16), pi-permuted columns within each 64-block --------
__global__ __launch_bounds__(256) void transpose_v(const u16* __restrict__ QKV,
                                                   u16* __restrict__ VT) {
  __shared__ u16 tile[32][33];
  int bh = blockIdx.z;
  int b = bh / NH, h = bh % NH;
  int sb = blockIdx.x * 32, db = blockIdx.y * 32;
  int tx = threadIdx.x, ty = threadIdx.y;
  const u16* src = QKV + (size_t)(b * SS) * E3 + 2 * D_EMB + h * DK;
  u16* dst = VT + (size_t)bh * DK * SS;
#pragma unroll
  for (int i = 0; i < 4; i++)
    tile[ty + i * 8][tx] = src[(size_t)(sb + ty + i * 8) * E3 + db + tx];
  __syncthreads();
  int s = sb + tx;
  int k6 = s & 63;
  int p = (s & ~63) | (k6 & 0x23) | ((k6 & 0x0C) << 1) | ((k6 & 0x10) >> 2);
#pragma unroll
  for (int i = 0; i < 4; i++)
    dst[(size_t)(db + ty + i * 8) * SS + p] = tile[tx][ty + i * 8];
}

// ---------------- bf16 GEMM, B given transposed ----------------
template <int OUTF32>
__global__ __launch_bounds__(256) void gemm_bt(const u16* __restrict__ A,
                                               const u16* __restrict__ Bt,
                                               void* __restrict__ Cout,
                                               int M, int N, int K, float scale) {
  __shared__ __align__(16) u16 As[128 * 32];
  __shared__ __align__(16) u16 Bs[128 * 32];
  int tid = threadIdx.x;
  int wave = tid >> 6, lane = tid & 63;
  int g = lane >> 4, nIdx = lane & 15;
  int m0 = blockIdx.y * 128, n0 = blockIdx.x * 128;
  int wm = (wave >> 1) * 64, wn = (wave & 1) * 64;

  f32x4 acc[4][4] = {};

  int row = tid >> 2, co = (tid & 3) * 8;
  int row2 = row + 64;

  for (int k0 = 0; k0 < K; k0 += 32) {
    __syncthreads();
    gload_lds16(A  + (size_t)(m0 + row)  * K + k0 + co, As + row  * 32 + co);
    gload_lds16(Bt + (size_t)(n0 + row)  * K + k0 + co, Bs + row  * 32 + co);
    gload_lds16(A  + (size_t)(m0 + row2) * K + k0 + co, As + row2 * 32 + co);
    gload_lds16(Bt + (size_t)(n0 + row2) * K + k0 + co, Bs + row2 * 32 + co);
    __syncthreads();

    bf16x8 af[4], bfr[4];
#pragma unroll
    for (int i = 0; i < 4; i++)
      af[i] = *(const bf16x8*)(As + (wm + i * 16 + nIdx) * 32 + g * 8);
#pragma unroll
    for (int j = 0; j < 4; j++)
      bfr[j] = *(const bf16x8*)(Bs + (wn + j * 16 + nIdx) * 32 + g * 8);
#pragma unroll
    for (int i = 0; i < 4; i++)
#pragma unroll
      for (int j = 0; j < 4; j++)
        acc[i][j] = mfma16(af[i], bfr[j], acc[i][j]);
  }

#pragma unroll
  for (int i = 0; i < 4; i++)
#pragma unroll
    for (int j = 0; j < 4; j++)
#pragma unroll
      for (int r = 0; r < 4; r++) {
        int rr = m0 + wm + i * 16 + g * 4 + r;
        int cc = n0 + wn + j * 16 + nIdx;
        float v = acc[i][j][r] * scale;
        if (OUTF32)
          ((float*)Cout)[(size_t)rr * N + cc] = v;
        else
          ((u16*)Cout)[(size_t)rr * N + cc] = f2bf(v);
      }
}

// ---------------- flash attention v6 ----------------
// v5 verified structure (4 waves = q-half x kv-stream, q=64/wave, stream merge
// via LDS, padded manual staging) with launch_bounds (256,2) to kill the v5
// register spill (798 MB scratch writes), and V-frag loads hoisted.
__global__ __launch_bounds__(256, 2) void flash(const u16* __restrict__ QKV,
                                                const u16* __restrict__ VT,
                                                u16* __restrict__ O) {
  // per stream: K tile 64x72 + V tile 64x72 (u16). 2 streams = 18432 u16 = 36864 B.
  __shared__ __align__(16) u16 smem[18432];

  int b = blockIdx.z, h = blockIdx.y;
  int q0 = blockIdx.x * 128;
  int tid = threadIdx.x, w = tid >> 6, l = tid & 63;
  int g = l >> 4, n = l & 15;
  int qh = w & 1, st = w >> 1;

  const u16* VTb = VT + (size_t)(b * NH + h) * DK * SS;
  u16* pKs = smem + st * 9216;
  u16* pVs = pKs + 4608;

  // --- Q fragments: 64 rows for this wave ---
  const u16* Qbase = QKV + (size_t)(b * SS + q0 + qh * 64) * E3 + h * DK;
  bf16x8 qf[4][2];
#pragma unroll
  for (int qg = 0; qg < 4; qg++)
#pragma unroll
    for (int hf = 0; hf < 2; hf++)
      qf[qg][hf] = *(const bf16x8*)(Qbase + (size_t)(qg * 16 + n) * E3 + hf * 32 + g * 8);

  f32x4 o_acc[4][4] = {};
  float lsum[4] = {0.f, 0.f, 0.f, 0.f};
  u32x4 onev = {0x3F803F80u, 0x3F803F80u, 0x3F803F80u, 0x3F803F80u};
  bf16x8 aone = __builtin_bit_cast(bf16x8, onev);

  // --- staging: even waves stage K of their stream, odd waves stage V ---
  int rL = l >> 3, cL = l & 7;
  const u16* g0;
  size_t rstep, tstep;
  u16* sW;
  if ((w & 1) == 0) {
    g0 = QKV + ((size_t)(b * SS) + st * 2048 + rL) * E3 + D_EMB + h * DK + cL * 8;
    rstep = (size_t)8 * E3;
    tstep = (size_t)64 * E3;
    sW = pKs + rL * 72 + cL * 8;
  } else {
    g0 = VTb + (size_t)rL * SS + st * 2048 + cL * 8;
    rstep = (size_t)8 * SS;
    tstep = 64;
    sW = pVs + rL * 72 + cL * 8;
  }

  uint4 pf[8];
#pragma unroll
  for (int i = 0; i < 8; i++)
    pf[i] = *(const uint4*)(g0 + i * rstep);

  for (int kt = 0; kt < 32; kt++) {
    __syncthreads();                          // previous tile's reads done
#pragma unroll
    for (int i = 0; i < 8; i++)
      *(uint4*)(sW + i * 576) = pf[i];        // row 8i+rL (72-stride), chunk cL
    __syncthreads();                          // writes visible

    if (kt < 31) {                            // prefetch next tile into regs
      const u16* gn = g0 + (size_t)(kt + 1) * tstep;
#pragma unroll
      for (int i = 0; i < 8; i++)
        pf[i] = *(const uint4*)(gn + i * rstep);
    }

#pragma unroll
    for (int s = 0; s < 2; s++) {             // 32-kv sub-round
      bf16x8 kf[2][2];
#pragma unroll
      for (int jj = 0; jj < 2; jj++)
#pragma unroll
        for (int hf = 0; hf < 2; hf++)
          kf[jj][hf] = *(const bf16x8*)(pKs + ((2 * s + jj) * 16 + n) * 72 + hf * 32 + g * 8);

      // QK^T for all 4 q-groups
      f32x4 C[4][2];
#pragma unroll
      for (int qg = 0; qg < 4; qg++)
#pragma unroll
        for (int jj = 0; jj < 2; jj++) {
          f32x4 t = {};
          t = mfma16(kf[jj][0], qf[qg][0], t);
          t = mfma16(kf[jj][1], qf[qg][1], t);
          C[qg][jj] = t;
        }

      // P = exp2(S^T), pack to PV B-frags; lsum via ones-MFMA
      u32x4 Bw[4];
#pragma unroll
      for (int qg = 0; qg < 4; qg++) {
#pragma unroll
        for (int jj = 0; jj < 2; jj++) {
          float p0 = exp2_fast(C[qg][jj][0]);
          float p1 = exp2_fast(C[qg][jj][1]);
          float p2 = exp2_fast(C[qg][jj][2]);
          float p3 = exp2_fast(C[qg][jj][3]);
          Bw[qg][jj * 2] = __builtin_amdgcn_perm(__builtin_bit_cast(unsigned, p1),
                                                 __builtin_bit_cast(unsigned, p0), 0x07060302u);
          Bw[qg][jj * 2 + 1] = __builtin_amdgcn_perm(__builtin_bit_cast(unsigned, p3),
                                                     __builtin_bit_cast(unsigned, p2), 0x07060302u);
        }
        f32x4 z = {};
        z = mfma16(aone, __builtin_bit_cast(bf16x8, Bw[qg]), z);
        lsum[qg] += z[0];
      }

      // O^T += V^T P^T, V-frag loaded once per dt (shared by all 4 q-groups)
#pragma unroll
      for (int dt = 0; dt < 4; dt++) {
        bf16x8 vf = *(const bf16x8*)(pVs + (dt * 16 + n) * 72 + s * 32 + g * 8);
#pragma unroll
        for (int qg = 0; qg < 4; qg++)
          o_acc[qg][dt] = mfma16(vf, __builtin_bit_cast(bf16x8, Bw[qg]), o_acc[qg][dt]);
      }
    }
  }

  __syncthreads();                            // all reads done before dump reuses smem

  // --- cross-wave merge: stream B dumps (O,l), stream A adds & writes ---
  float* dumpF = (float*)smem;
  if (w >= 2) {
    float* dst = dumpF + ((size_t)((w - 2) * 64 + l)) * 68;
#pragma unroll
    for (int qg = 0; qg < 4; qg++)
#pragma unroll
      for (int dt = 0; dt < 4; dt++)
        *(f32x4*)(dst + (qg * 4 + dt) * 4) = o_acc[qg][dt];
    f32x4 lv = {lsum[0], lsum[1], lsum[2], lsum[3]};
    *(f32x4*)(dst + 64) = lv;
  }
  __syncthreads();
  if (w < 2) {
    float* src = dumpF + ((size_t)(w * 64 + l)) * 68;
#pragma unroll
    for (int qg = 0; qg < 4; qg++)
#pragma unroll
      for (int dt = 0; dt < 4; dt++)
        o_acc[qg][dt] += *(f32x4*)(src + (qg * 4 + dt) * 4);
    f32x4 lv = *(f32x4*)(src + 64);
#pragma unroll
    for (int qg = 0; qg < 4; qg++) {
      float rl = rcp_fast(lsum[qg] + lv[qg]);
      u16* Obp = O + (size_t)(b * SS + q0 + w * 64 + qg * 16 + n) * D_EMB + h * DK;
#pragma unroll
      for (int dt = 0; dt < 4; dt++) {
        uint2 pk;
        pk.x = (unsigned)f2bf(o_acc[qg][dt][0] * rl) |
               ((unsigned)f2bf(o_acc[qg][dt][1] * rl) << 16);
        pk.y = (unsigned)f2bf(o_acc[qg][dt][2] * rl) |
               ((unsigned)f2bf(o_acc[qg][dt][3] * rl) << 16);
        *(uint2*)(Obp + dt * 16 + g * 4) = pk;
      }
    }
  }
}

extern "C" void kernel_launch(void* const* d_in, const int* in_sizes, int n_in,
                              void* d_out, int out_size, void* d_ws, size_t ws_size,
                              hipStream_t stream) {
  const float* X  = (const float*)d_in[0];
  const float* Wq = (const float*)d_in[1];
  const float* Wk = (const float*)d_in[2];
  const float* Wv = (const float*)d_in[3];
  const float* Wo = (const float*)d_in[4];
  float* out = (float*)d_out;

  u16* Xb    = (u16*)d_ws;                         // MM*D_EMB
  u16* WTqkv = Xb + (size_t)MM * D_EMB;            // E3*D_EMB
  u16* WoT   = WTqkv + (size_t)E3 * D_EMB;         // D_EMB*D_EMB
  u16* QKV   = WoT + (size_t)D_EMB * D_EMB;        // MM*E3
  u16* VT    = QKV + (size_t)MM * E3;              // NB*NH*DK*SS
  u16* Ob    = VT + (size_t)NB * NH * DK * SS;     // MM*D_EMB

  dim3 tb(32, 8);
  cast_kernel<<<(MM * D_EMB) / 1024, 256, 0, stream>>>(X, Xb, MM * D_EMB);
  transpose_cast_all<<<dim3(24, 24, 4), tb, 0, stream>>>(Wq, Wk, Wv, Wo, WTqkv, WoT,
                                                         0.125f * 1.4426950408889634f);
  gemm_bt<0><<<dim3(E3 / 128, MM / 128), 256, 0, stream>>>(Xb, WTqkv, (void*)QKV,
                                                           MM, E3, D_EMB, 1.0f);
  transpose_v<<<dim3(SS / 32, 2, NB * NH), tb, 0, stream>>>(QKV, VT);
  flash<<<dim3(SS / 128, NH, NB), 256, 0, stream>>>(QKV, VT, Ob);
  gemm_bt<1><<<dim3(D_EMB / 128, MM / 128), 256, 0, stream>>>(Ob, WoT, (void*)out,
                                                              MM, D_EMB, D_EMB, 1.0f);
}

// Round 7
// 293.560 us; speedup vs baseline: 1.3970x; 1.3942x over previous
//
#include <hip/hip_runtime.h>

#define D_EMB 768
#define NH 12
#define DK 64
#define NB 2
#define SS 4096
#define E3 (3*D_EMB)   // 2304
#define MM (NB*SS)     // 8192

typedef unsigned short u16;
typedef __attribute__((ext_vector_type(8))) __bf16 bf16x8;
typedef __attribute__((ext_vector_type(4))) float f32x4;
typedef __attribute__((ext_vector_type(4))) unsigned int u32x4;

static __device__ __forceinline__ u16 f2bf(float f) {
  unsigned u = __builtin_bit_cast(unsigned, f);
  u += 0x7fffu + ((u >> 16) & 1u);          // round-to-nearest-even
  return (u16)(u >> 16);
}
static __device__ __forceinline__ f32x4 mfma16(bf16x8 a, bf16x8 b, f32x4 c) {
  return __builtin_amdgcn_mfma_f32_16x16x32_bf16(a, b, c, 0, 0, 0);
}
static __device__ __forceinline__ float exp2_fast(float x) {
#if __has_builtin(__builtin_amdgcn_exp2f)
  return __builtin_amdgcn_exp2f(x);
#else
  return __builtin_exp2f(x);
#endif
}
static __device__ __forceinline__ float rcp_fast(float x) {
#if __has_builtin(__builtin_amdgcn_rcpf)
  return __builtin_amdgcn_rcpf(x);
#else
  return 1.f / x;
#endif
}
static __device__ __forceinline__ void gload_lds16(const u16* g, u16* l) {
  __builtin_amdgcn_global_load_lds((const __attribute__((address_space(1))) void*)g,
                                   (__attribute__((address_space(3))) void*)l, 16, 0, 0);
}

// ---------------- cast fp32 -> bf16, elementwise ----------------
__global__ __launch_bounds__(256) void cast_kernel(const float* __restrict__ in,
                                                   u16* __restrict__ out, int n) {
  int i = (blockIdx.x * 256 + threadIdx.x) * 4;
  if (i + 3 < n) {
    float4 v = *(const float4*)(in + i);
    out[i + 0] = f2bf(v.x);
    out[i + 1] = f2bf(v.y);
    out[i + 2] = f2bf(v.z);
    out[i + 3] = f2bf(v.w);
  }
}

// -------- transpose + cast all four weights (z selects): WT[n][k] = W[k][n] * scale --------
__global__ __launch_bounds__(256) void transpose_cast_all(const float* __restrict__ Wq,
                                                          const float* __restrict__ Wk,
                                                          const float* __restrict__ Wv,
                                                          const float* __restrict__ Wo,
                                                          u16* __restrict__ WTqkv,
                                                          u16* __restrict__ WoT, float qscale) {
  __shared__ float tile[32][33];
  int z = blockIdx.z;
  const float* W = (z == 0) ? Wq : (z == 1) ? Wk : (z == 2) ? Wv : Wo;
  u16* WT = (z < 3) ? WTqkv + (size_t)z * D_EMB * D_EMB : WoT;
  float scale = (z == 0) ? qscale : 1.0f;
  int kb = blockIdx.y * 32, nb = blockIdx.x * 32;
  int tx = threadIdx.x, ty = threadIdx.y;
#pragma unroll
  for (int i = 0; i < 4; i++)
    tile[ty + i * 8][tx] = W[(size_t)(kb + ty + i * 8) * D_EMB + nb + tx];
  __syncthreads();
#pragma unroll
  for (int i = 0; i < 4; i++)
    WT[(size_t)(nb + ty + i * 8) * D_EMB + kb + tx] = f2bf(tile[tx][ty + i * 8] * scale);
}

// -------- transpose V (bf16), pi-permuted columns within each 64-block --------
__global__ __launch_bounds__(256) void transpose_v(const u16* __restrict__ QKV,
                                                   u16* __restrict__ VT) {
  __shared__ u16 tile[32][33];
  int bh = blockIdx.z;
  int b = bh / NH, h = bh % NH;
  int sb = blockIdx.x * 32, db = blockIdx.y * 32;
  int tx = threadIdx.x, ty = threadIdx.y;
  const u16* src = QKV + (size_t)(b * SS) * E3 + 2 * D_EMB + h * DK;
  u16* dst = VT + (size_t)bh * DK * SS;
#pragma unroll
  for (int i = 0; i < 4; i++)
    tile[ty + i * 8][tx] = src[(size_t)(sb + ty + i * 8) * E3 + db + tx];
  __syncthreads();
  int s = sb + tx;
  int k6 = s & 63;
  int p = (s & ~63) | (k6 & 0x23) | ((k6 & 0x0C) << 1) | ((k6 & 0x10) >> 2);
#pragma unroll
  for (int i = 0; i < 4; i++)
    dst[(size_t)(db + ty + i * 8) * SS + p] = tile[tx][ty + i * 8];
}

// ---------------- bf16 GEMM, B given transposed ----------------
template <int OUTF32>
__global__ __launch_bounds__(256) void gemm_bt(const u16* __restrict__ A,
                                               const u16* __restrict__ Bt,
                                               void* __restrict__ Cout,
                                               int M, int N, int K, float scale) {
  __shared__ __align__(16) u16 As[128 * 32];
  __shared__ __align__(16) u16 Bs[128 * 32];
  int tid = threadIdx.x;
  int wave = tid >> 6, lane = tid & 63;
  int g = lane >> 4, nIdx = lane & 15;
  int m0 = blockIdx.y * 128, n0 = blockIdx.x * 128;
  int wm = (wave >> 1) * 64, wn = (wave & 1) * 64;

  f32x4 acc[4][4] = {};

  int row = tid >> 2, co = (tid & 3) * 8;
  int row2 = row + 64;

  for (int k0 = 0; k0 < K; k0 += 32) {
    __syncthreads();
    gload_lds16(A  + (size_t)(m0 + row)  * K + k0 + co, As + row  * 32 + co);
    gload_lds16(Bt + (size_t)(n0 + row)  * K + k0 + co, Bs + row  * 32 + co);
    gload_lds16(A  + (size_t)(m0 + row2) * K + k0 + co, As + row2 * 32 + co);
    gload_lds16(Bt + (size_t)(n0 + row2) * K + k0 + co, Bs + row2 * 32 + co);
    __syncthreads();

    bf16x8 af[4], bfr[4];
#pragma unroll
    for (int i = 0; i < 4; i++)
      af[i] = *(const bf16x8*)(As + (wm + i * 16 + nIdx) * 32 + g * 8);
#pragma unroll
    for (int j = 0; j < 4; j++)
      bfr[j] = *(const bf16x8*)(Bs + (wn + j * 16 + nIdx) * 32 + g * 8);
#pragma unroll
    for (int i = 0; i < 4; i++)
#pragma unroll
      for (int j = 0; j < 4; j++)
        acc[i][j] = mfma16(af[i], bfr[j], acc[i][j]);
  }

#pragma unroll
  for (int i = 0; i < 4; i++)
#pragma unroll
    for (int j = 0; j < 4; j++)
#pragma unroll
      for (int r = 0; r < 4; r++) {
        int rr = m0 + wm + i * 16 + g * 4 + r;
        int cc = n0 + wn + j * 16 + nIdx;
        float v = acc[i][j][r] * scale;
        if (OUTF32)
          ((float*)Cout)[(size_t)rr * N + cc] = v;
        else
          ((u16*)Cout)[(size_t)rr * N + cc] = f2bf(v);
      }
}

// ---------------- flash attention v8 ----------------
// = verified v5 algorithm (4 waves = q-half x kv-stream, q=64/wave, padded
// manual staging, LDS stream-merge) with the register footprint cut to fit
// the allocator's VGPR partition: no cross-iteration pf[] prefetch (tile
// loaded inside the staging window), q-pair compute loop (C[2][2]/Bw[2]).
__global__ __launch_bounds__(256, 2) void flash(const u16* __restrict__ QKV,
                                                const u16* __restrict__ VT,
                                                u16* __restrict__ O) {
  // per stream: K tile 64x72 + V tile 64x72 (u16). 2 streams = 18432 u16 = 36864 B.
  __shared__ __align__(16) u16 smem[18432];

  int b = blockIdx.z, h = blockIdx.y;
  int q0 = blockIdx.x * 128;
  int tid = threadIdx.x, w = tid >> 6, l = tid & 63;
  int g = l >> 4, n = l & 15;
  int qh = w & 1, st = w >> 1;

  const u16* VTb = VT + (size_t)(b * NH + h) * DK * SS;
  u16* pKs = smem + st * 9216;
  u16* pVs = pKs + 4608;

  // --- Q fragments: 64 rows for this wave ---
  const u16* Qbase = QKV + (size_t)(b * SS + q0 + qh * 64) * E3 + h * DK;
  bf16x8 qf[4][2];
#pragma unroll
  for (int qg = 0; qg < 4; qg++)
#pragma unroll
    for (int hf = 0; hf < 2; hf++)
      qf[qg][hf] = *(const bf16x8*)(Qbase + (size_t)(qg * 16 + n) * E3 + hf * 32 + g * 8);

  f32x4 o_acc[4][4] = {};
  float lsum[4] = {0.f, 0.f, 0.f, 0.f};
  u32x4 onev = {0x3F803F80u, 0x3F803F80u, 0x3F803F80u, 0x3F803F80u};
  bf16x8 aone = __builtin_bit_cast(bf16x8, onev);

  // --- staging: even waves stage K of their stream, odd waves stage V ---
  int rL = l >> 3, cL = l & 7;
  const u16* g0;
  size_t rstep, tstep;
  u16* sW;
  if ((w & 1) == 0) {
    g0 = QKV + ((size_t)(b * SS) + st * 2048 + rL) * E3 + D_EMB + h * DK + cL * 8;
    rstep = (size_t)8 * E3;
    tstep = (size_t)64 * E3;
    sW = pKs + rL * 72 + cL * 8;
  } else {
    g0 = VTb + (size_t)rL * SS + st * 2048 + cL * 8;
    rstep = (size_t)8 * SS;
    tstep = 64;
    sW = pVs + rL * 72 + cL * 8;
  }

  for (int kt = 0; kt < 32; kt++) {
    __syncthreads();                          // previous tile's reads done
    {
      const u16* gn = g0 + (size_t)kt * tstep;
      uint4 t[8];
#pragma unroll
      for (int i = 0; i < 8; i++)
        t[i] = *(const uint4*)(gn + i * rstep);
#pragma unroll
      for (int i = 0; i < 8; i++)
        *(uint4*)(sW + i * 576) = t[i];       // row 8i+rL (72-stride), chunk cL
    }
    __syncthreads();                          // writes visible

#pragma unroll
    for (int s = 0; s < 2; s++) {             // 32-kv sub-round
      bf16x8 kf[2][2];
#pragma unroll
      for (int jj = 0; jj < 2; jj++)
#pragma unroll
        for (int hf = 0; hf < 2; hf++)
          kf[jj][hf] = *(const bf16x8*)(pKs + ((2 * s + jj) * 16 + n) * 72 + hf * 32 + g * 8);

#pragma unroll
      for (int p = 0; p < 2; p++) {           // q-group pair
        f32x4 C[2][2];
#pragma unroll
        for (int q2 = 0; q2 < 2; q2++) {
          int qg = 2 * p + q2;
#pragma unroll
          for (int jj = 0; jj < 2; jj++) {
            f32x4 t = {};
            t = mfma16(kf[jj][0], qf[qg][0], t);
            t = mfma16(kf[jj][1], qf[qg][1], t);
            C[q2][jj] = t;
          }
        }
        u32x4 Bw[2];
#pragma unroll
        for (int q2 = 0; q2 < 2; q2++)
#pragma unroll
          for (int jj = 0; jj < 2; jj++) {
            float p0 = exp2_fast(C[q2][jj][0]);
            float p1 = exp2_fast(C[q2][jj][1]);
            float p2 = exp2_fast(C[q2][jj][2]);
            float p3 = exp2_fast(C[q2][jj][3]);
            Bw[q2][jj * 2] = __builtin_amdgcn_perm(__builtin_bit_cast(unsigned, p1),
                                                   __builtin_bit_cast(unsigned, p0), 0x07060302u);
            Bw[q2][jj * 2 + 1] = __builtin_amdgcn_perm(__builtin_bit_cast(unsigned, p3),
                                                       __builtin_bit_cast(unsigned, p2), 0x07060302u);
          }
#pragma unroll
        for (int q2 = 0; q2 < 2; q2++) {
          f32x4 z = {};
          z = mfma16(aone, __builtin_bit_cast(bf16x8, Bw[q2]), z);
          lsum[2 * p + q2] += z[0];
        }
#pragma unroll
        for (int dt = 0; dt < 4; dt++) {
          bf16x8 vf = *(const bf16x8*)(pVs + (dt * 16 + n) * 72 + s * 32 + g * 8);
#pragma unroll
          for (int q2 = 0; q2 < 2; q2++)
            o_acc[2 * p + q2][dt] = mfma16(vf, __builtin_bit_cast(bf16x8, Bw[q2]),
                                           o_acc[2 * p + q2][dt]);
        }
      }
    }
  }

  __syncthreads();                            // all reads done before dump reuses smem

  // --- cross-wave merge: stream B dumps (O,l), stream A adds & writes ---
  float* dumpF = (float*)smem;
  if (w >= 2) {
    float* dst = dumpF + ((size_t)((w - 2) * 64 + l)) * 68;
#pragma unroll
    for (int qg = 0; qg < 4; qg++)
#pragma unroll
      for (int dt = 0; dt < 4; dt++)
        *(f32x4*)(dst + (qg * 4 + dt) * 4) = o_acc[qg][dt];
    f32x4 lv = {lsum[0], lsum[1], lsum[2], lsum[3]};
    *(f32x4*)(dst + 64) = lv;
  }
  __syncthreads();
  if (w < 2) {
    float* src = dumpF + ((size_t)(w * 64 + l)) * 68;
#pragma unroll
    for (int qg = 0; qg < 4; qg++)
#pragma unroll
      for (int dt = 0; dt < 4; dt++)
        o_acc[qg][dt] += *(f32x4*)(src + (qg * 4 + dt) * 4);
    f32x4 lv = *(f32x4*)(src + 64);
#pragma unroll
    for (int qg = 0; qg < 4; qg++) {
      float rl = rcp_fast(lsum[qg] + lv[qg]);
      u16* Obp = O + (size_t)(b * SS + q0 + w * 64 + qg * 16 + n) * D_EMB + h * DK;
#pragma unroll
      for (int dt = 0; dt < 4; dt++) {
        uint2 pk;
        pk.x = (unsigned)f2bf(o_acc[qg][dt][0] * rl) |
               ((unsigned)f2bf(o_acc[qg][dt][1] * rl) << 16);
        pk.y = (unsigned)f2bf(o_acc[qg][dt][2] * rl) |
               ((unsigned)f2bf(o_acc[qg][dt][3] * rl) << 16);
        *(uint2*)(Obp + dt * 16 + g * 4) = pk;
      }
    }
  }
}

extern "C" void kernel_launch(void* const* d_in, const int* in_sizes, int n_in,
                              void* d_out, int out_size, void* d_ws, size_t ws_size,
                              hipStream_t stream) {
  const float* X  = (const float*)d_in[0];
  const float* Wq = (const float*)d_in[1];
  const float* Wk = (const float*)d_in[2];
  const float* Wv = (const float*)d_in[3];
  const float* Wo = (const float*)d_in[4];
  float* out = (float*)d_out;

  u16* Xb    = (u16*)d_ws;                         // MM*D_EMB
  u16* WTqkv = Xb + (size_t)MM * D_EMB;            // E3*D_EMB
  u16* WoT   = WTqkv + (size_t)E3 * D_EMB;         // D_EMB*D_EMB
  u16* QKV   = WoT + (size_t)D_EMB * D_EMB;        // MM*E3
  u16* VT    = QKV + (size_t)MM * E3;              // NB*NH*DK*SS
  u16* Ob    = VT + (size_t)NB * NH * DK * SS;     // MM*D_EMB

  dim3 tb(32, 8);
  cast_kernel<<<(MM * D_EMB) / 1024, 256, 0, stream>>>(X, Xb, MM * D_EMB);
  transpose_cast_all<<<dim3(24, 24, 4), tb, 0, stream>>>(Wq, Wk, Wv, Wo, WTqkv, WoT,
                                                         0.125f * 1.4426950408889634f);
  gemm_bt<0><<<dim3(E3 / 128, MM / 128), 256, 0, stream>>>(Xb, WTqkv, (void*)QKV,
                                                           MM, E3, D_EMB, 1.0f);
  transpose_v<<<dim3(SS / 32, 2, NB * NH), tb, 0, stream>>>(QKV, VT);
  flash<<<dim3(SS / 128, NH, NB), 256, 0, stream>>>(QKV, VT, Ob);
  gemm_bt<1><<<dim3(D_EMB / 128, MM / 128), 256, 0, stream>>>(Ob, WoT, (void*)out,
                                                              MM, D_EMB, D_EMB, 1.0f);
}

// Round 8
// 260.047 us; speedup vs baseline: 1.5770x; 1.1289x over previous
//
#include <hip/hip_runtime.h>

#define D_EMB 768
#define NH 12
#define DK 64
#define NB 2
#define SS 4096
#define E3 (3*D_EMB)   // 2304
#define MM (NB*SS)     // 8192

typedef unsigned short u16;
typedef __attribute__((ext_vector_type(8))) __bf16 bf16x8;
typedef __attribute__((ext_vector_type(4))) float f32x4;
typedef __attribute__((ext_vector_type(4))) unsigned int u32x4;

static __device__ __forceinline__ u16 f2bf(float f) {
  unsigned u = __builtin_bit_cast(unsigned, f);
  u += 0x7fffu + ((u >> 16) & 1u);          // round-to-nearest-even
  return (u16)(u >> 16);
}
static __device__ __forceinline__ f32x4 mfma16(bf16x8 a, bf16x8 b, f32x4 c) {
  return __builtin_amdgcn_mfma_f32_16x16x32_bf16(a, b, c, 0, 0, 0);
}
static __device__ __forceinline__ float exp2_fast(float x) {
#if __has_builtin(__builtin_amdgcn_exp2f)
  return __builtin_amdgcn_exp2f(x);
#else
  return __builtin_exp2f(x);
#endif
}
static __device__ __forceinline__ float rcp_fast(float x) {
#if __has_builtin(__builtin_amdgcn_rcpf)
  return __builtin_amdgcn_rcpf(x);
#else
  return 1.f / x;
#endif
}
static __device__ __forceinline__ void gload_lds16(const u16* g, u16* l) {
  __builtin_amdgcn_global_load_lds((const __attribute__((address_space(1))) void*)g,
                                   (__attribute__((address_space(3))) void*)l, 16, 0, 0);
}

// ---------------- cast fp32 -> bf16, elementwise ----------------
__global__ __launch_bounds__(256) void cast_kernel(const float* __restrict__ in,
                                                   u16* __restrict__ out, int n) {
  int i = (blockIdx.x * 256 + threadIdx.x) * 4;
  if (i + 3 < n) {
    float4 v = *(const float4*)(in + i);
    out[i + 0] = f2bf(v.x);
    out[i + 1] = f2bf(v.y);
    out[i + 2] = f2bf(v.z);
    out[i + 3] = f2bf(v.w);
  }
}

// -------- transpose + cast all four weights (z selects): WT[n][k] = W[k][n] * scale --------
__global__ __launch_bounds__(256) void transpose_cast_all(const float* __restrict__ Wq,
                                                          const float* __restrict__ Wk,
                                                          const float* __restrict__ Wv,
                                                          const float* __restrict__ Wo,
                                                          u16* __restrict__ WTqkv,
                                                          u16* __restrict__ WoT, float qscale) {
  __shared__ float tile[32][33];
  int z = blockIdx.z;
  const float* W = (z == 0) ? Wq : (z == 1) ? Wk : (z == 2) ? Wv : Wo;
  u16* WT = (z < 3) ? WTqkv + (size_t)z * D_EMB * D_EMB : WoT;
  float scale = (z == 0) ? qscale : 1.0f;
  int kb = blockIdx.y * 32, nb = blockIdx.x * 32;
  int tx = threadIdx.x, ty = threadIdx.y;
#pragma unroll
  for (int i = 0; i < 4; i++)
    tile[ty + i * 8][tx] = W[(size_t)(kb + ty + i * 8) * D_EMB + nb + tx];
  __syncthreads();
#pragma unroll
  for (int i = 0; i < 4; i++)
    WT[(size_t)(nb + ty + i * 8) * D_EMB + kb + tx] = f2bf(tile[tx][ty + i * 8] * scale);
}

// -------- transpose V (bf16), pi-permuted columns within each 64-block --------
__global__ __launch_bounds__(256) void transpose_v(const u16* __restrict__ QKV,
                                                   u16* __restrict__ VT) {
  __shared__ u16 tile[32][33];
  int bh = blockIdx.z;
  int b = bh / NH, h = bh % NH;
  int sb = blockIdx.x * 32, db = blockIdx.y * 32;
  int tx = threadIdx.x, ty = threadIdx.y;
  const u16* src = QKV + (size_t)(b * SS) * E3 + 2 * D_EMB + h * DK;
  u16* dst = VT + (size_t)bh * DK * SS;
#pragma unroll
  for (int i = 0; i < 4; i++)
    tile[ty + i * 8][tx] = src[(size_t)(sb + ty + i * 8) * E3 + db + tx];
  __syncthreads();
  int s = sb + tx;
  int k6 = s & 63;
  int p = (s & ~63) | (k6 & 0x23) | ((k6 & 0x0C) << 1) | ((k6 & 0x10) >> 2);
#pragma unroll
  for (int i = 0; i < 4; i++)
    dst[(size_t)(db + ty + i * 8) * SS + p] = tile[tx][ty + i * 8];
}

// ---------------- bf16 GEMM, B given transposed ----------------
template <int OUTF32>
__global__ __launch_bounds__(256) void gemm_bt(const u16* __restrict__ A,
                                               const u16* __restrict__ Bt,
                                               void* __restrict__ Cout,
                                               int M, int N, int K, float scale) {
  __shared__ __align__(16) u16 As[128 * 32];
  __shared__ __align__(16) u16 Bs[128 * 32];
  int tid = threadIdx.x;
  int wave = tid >> 6, lane = tid & 63;
  int g = lane >> 4, nIdx = lane & 15;
  int m0 = blockIdx.y * 128, n0 = blockIdx.x * 128;
  int wm = (wave >> 1) * 64, wn = (wave & 1) * 64;

  f32x4 acc[4][4] = {};

  int row = tid >> 2, co = (tid & 3) * 8;
  int row2 = row + 64;

  for (int k0 = 0; k0 < K; k0 += 32) {
    __syncthreads();
    gload_lds16(A  + (size_t)(m0 + row)  * K + k0 + co, As + row  * 32 + co);
    gload_lds16(Bt + (size_t)(n0 + row)  * K + k0 + co, Bs + row  * 32 + co);
    gload_lds16(A  + (size_t)(m0 + row2) * K + k0 + co, As + row2 * 32 + co);
    gload_lds16(Bt + (size_t)(n0 + row2) * K + k0 + co, Bs + row2 * 32 + co);
    __syncthreads();

    bf16x8 af[4], bfr[4];
#pragma unroll
    for (int i = 0; i < 4; i++)
      af[i] = *(const bf16x8*)(As + (wm + i * 16 + nIdx) * 32 + g * 8);
#pragma unroll
    for (int j = 0; j < 4; j++)
      bfr[j] = *(const bf16x8*)(Bs + (wn + j * 16 + nIdx) * 32 + g * 8);
#pragma unroll
    for (int i = 0; i < 4; i++)
#pragma unroll
      for (int j = 0; j < 4; j++)
        acc[i][j] = mfma16(af[i], bfr[j], acc[i][j]);
  }

#pragma unroll
  for (int i = 0; i < 4; i++)
#pragma unroll
    for (int j = 0; j < 4; j++)
#pragma unroll
      for (int r = 0; r < 4; r++) {
        int rr = m0 + wm + i * 16 + g * 4 + r;
        int cc = n0 + wn + j * 16 + nIdx;
        float v = acc[i][j][r] * scale;
        if (OUTF32)
          ((float*)Cout)[(size_t)rr * N + cc] = v;
        else
          ((u16*)Cout)[(size_t)rr * N + cc] = f2bf(v);
      }
}

// ---------------- flash attention v9 ----------------
// v8's verified compute (4 waves = q-half x kv-stream, q=64/wave, LDS stream
// merge) with async double-buffered global_load_lds staging:
//  - per-lane LDS dest = base + lane*16B (the gemm_bt-proven gll form)
//  - XOR source swizzle: LDS[r][c] = G[r][c^(r&7)]; reads use (chunk^(n&7))
//  - ONE barrier per ktile; prefetch glls fly across the whole compute phase
__global__ __launch_bounds__(256, 2) void flash(const u16* __restrict__ QKV,
                                                const u16* __restrict__ VT,
                                                u16* __restrict__ O) {
  // [stream][buf][K 4096 u16][V 4096 u16] = 32768 u16 = 64 KB
  __shared__ __align__(16) u16 smem[32768];

  int b = blockIdx.z, h = blockIdx.y;
  int q0 = blockIdx.x * 128;
  int tid = threadIdx.x, w = tid >> 6, l = tid & 63;
  int g = l >> 4, n = l & 15;
  int qh = w & 1, st = w >> 1;

  const u16* VTb = VT + (size_t)(b * NH + h) * DK * SS;
  u16* sbase = smem + st * 16384;             // this stream's double buffer

  // --- Q fragments: 64 rows for this wave ---
  const u16* Qbase = QKV + (size_t)(b * SS + q0 + qh * 64) * E3 + h * DK;
  bf16x8 qf[4][2];
#pragma unroll
  for (int qg = 0; qg < 4; qg++)
#pragma unroll
    for (int hf = 0; hf < 2; hf++)
      qf[qg][hf] = *(const bf16x8*)(Qbase + (size_t)(qg * 16 + n) * E3 + hf * 32 + g * 8);

  f32x4 o_acc[4][4] = {};
  float lsum[4] = {0.f, 0.f, 0.f, 0.f};
  u32x4 onev = {0x3F803F80u, 0x3F803F80u, 0x3F803F80u, 0x3F803F80u};
  bf16x8 aone = __builtin_bit_cast(bf16x8, onev);

  // --- staging: even waves stage K of their stream, odd waves stage V ---
  int rL = l >> 3, cL = l & 7;
  int xr8 = (cL ^ rL) * 8;                    // source-side XOR swizzle
  const u16* g0;
  size_t rstep, tstep;
  u16* sd0;                                   // per-lane LDS dest: uniform + l*16B
  if ((w & 1) == 0) {
    g0 = QKV + ((size_t)(b * SS) + st * 2048 + rL) * E3 + D_EMB + h * DK + xr8;
    rstep = (size_t)8 * E3;
    tstep = (size_t)64 * E3;
    sd0 = sbase + l * 8;
  } else {
    g0 = VTb + (size_t)rL * SS + st * 2048 + xr8;
    rstep = (size_t)8 * SS;
    tstep = 64;
    sd0 = sbase + 4096 + l * 8;
  }

  // prologue: stage tile 0 into buffer 0
#pragma unroll
  for (int i = 0; i < 8; i++)
    gload_lds16(g0 + i * rstep, sd0 + i * 512);

  int xrn = (n & 7);
  for (int kt = 0; kt < 32; kt++) {
    __syncthreads();                          // buf[kt&1] glls complete & visible

    const u16* pK = sbase + (kt & 1) * 8192;
    const u16* pV = pK + 4096;

    if (kt < 31) {                            // async prefetch into buf[(kt+1)&1]
      const u16* gn = g0 + (size_t)(kt + 1) * tstep;
      u16* sd = sd0 + ((kt + 1) & 1) * 8192;
#pragma unroll
      for (int i = 0; i < 8; i++)
        gload_lds16(gn + i * rstep, sd + i * 512);
    }

#pragma unroll
    for (int s = 0; s < 2; s++) {             // 32-kv sub-round
      bf16x8 kf[2][2];
#pragma unroll
      for (int jj = 0; jj < 2; jj++)
#pragma unroll
        for (int hf = 0; hf < 2; hf++)
          kf[jj][hf] = *(const bf16x8*)(pK + ((2 * s + jj) * 16 + n) * 64 +
                                        ((hf * 4 + g) ^ xrn) * 8);

#pragma unroll
      for (int p = 0; p < 2; p++) {           // q-group pair
        f32x4 C[2][2];
#pragma unroll
        for (int q2 = 0; q2 < 2; q2++) {
          int qg = 2 * p + q2;
#pragma unroll
          for (int jj = 0; jj < 2; jj++) {
            f32x4 t = {};
            t = mfma16(kf[jj][0], qf[qg][0], t);
            t = mfma16(kf[jj][1], qf[qg][1], t);
            C[q2][jj] = t;
          }
        }
        u32x4 Bw[2];
#pragma unroll
        for (int q2 = 0; q2 < 2; q2++)
#pragma unroll
          for (int jj = 0; jj < 2; jj++) {
            float p0 = exp2_fast(C[q2][jj][0]);
            float p1 = exp2_fast(C[q2][jj][1]);
            float p2 = exp2_fast(C[q2][jj][2]);
            float p3 = exp2_fast(C[q2][jj][3]);
            Bw[q2][jj * 2] = __builtin_amdgcn_perm(__builtin_bit_cast(unsigned, p1),
                                                   __builtin_bit_cast(unsigned, p0), 0x07060302u);
            Bw[q2][jj * 2 + 1] = __builtin_amdgcn_perm(__builtin_bit_cast(unsigned, p3),
                                                       __builtin_bit_cast(unsigned, p2), 0x07060302u);
          }
#pragma unroll
        for (int q2 = 0; q2 < 2; q2++) {
          f32x4 z = {};
          z = mfma16(aone, __builtin_bit_cast(bf16x8, Bw[q2]), z);
          lsum[2 * p + q2] += z[0];
        }
#pragma unroll
        for (int dt = 0; dt < 4; dt++) {
          bf16x8 vf = *(const bf16x8*)(pV + (dt * 16 + n) * 64 +
                                       ((s * 4 + g) ^ xrn) * 8);
#pragma unroll
          for (int q2 = 0; q2 < 2; q2++)
            o_acc[2 * p + q2][dt] = mfma16(vf, __builtin_bit_cast(bf16x8, Bw[q2]),
                                           o_acc[2 * p + q2][dt]);
        }
      }
    }
  }

  __syncthreads();                            // all reads done before dump reuses smem

  // --- cross-wave merge: stream B dumps (O,l), stream A adds & writes ---
  float* dumpF = (float*)smem;
  if (w >= 2) {
    float* dst = dumpF + ((size_t)((w - 2) * 64 + l)) * 68;
#pragma unroll
    for (int qg = 0; qg < 4; qg++)
#pragma unroll
      for (int dt = 0; dt < 4; dt++)
        *(f32x4*)(dst + (qg * 4 + dt) * 4) = o_acc[qg][dt];
    f32x4 lv = {lsum[0], lsum[1], lsum[2], lsum[3]};
    *(f32x4*)(dst + 64) = lv;
  }
  __syncthreads();
  if (w < 2) {
    float* src = dumpF + ((size_t)(w * 64 + l)) * 68;
#pragma unroll
    for (int qg = 0; qg < 4; qg++)
#pragma unroll
      for (int dt = 0; dt < 4; dt++)
        o_acc[qg][dt] += *(f32x4*)(src + (qg * 4 + dt) * 4);
    f32x4 lv = *(f32x4*)(src + 64);
#pragma unroll
    for (int qg = 0; qg < 4; qg++) {
      float rl = rcp_fast(lsum[qg] + lv[qg]);
      u16* Obp = O + (size_t)(b * SS + q0 + w * 64 + qg * 16 + n) * D_EMB + h * DK;
#pragma unroll
      for (int dt = 0; dt < 4; dt++) {
        uint2 pk;
        pk.x = (unsigned)f2bf(o_acc[qg][dt][0] * rl) |
               ((unsigned)f2bf(o_acc[qg][dt][1] * rl) << 16);
        pk.y = (unsigned)f2bf(o_acc[qg][dt][2] * rl) |
               ((unsigned)f2bf(o_acc[qg][dt][3] * rl) << 16);
        *(uint2*)(Obp + dt * 16 + g * 4) = pk;
      }
    }
  }
}

extern "C" void kernel_launch(void* const* d_in, const int* in_sizes, int n_in,
                              void* d_out, int out_size, void* d_ws, size_t ws_size,
                              hipStream_t stream) {
  const float* X  = (const float*)d_in[0];
  const float* Wq = (const float*)d_in[1];
  const float* Wk = (const float*)d_in[2];
  const float* Wv = (const float*)d_in[3];
  const float* Wo = (const float*)d_in[4];
  float* out = (float*)d_out;

  u16* Xb    = (u16*)d_ws;                         // MM*D_EMB
  u16* WTqkv = Xb + (size_t)MM * D_EMB;            // E3*D_EMB
  u16* WoT   = WTqkv + (size_t)E3 * D_EMB;         // D_EMB*D_EMB
  u16* QKV   = WoT + (size_t)D_EMB * D_EMB;        // MM*E3
  u16* VT    = QKV + (size_t)MM * E3;              // NB*NH*DK*SS
  u16* Ob    = VT + (size_t)NB * NH * DK * SS;     // MM*D_EMB

  dim3 tb(32, 8);
  cast_kernel<<<(MM * D_EMB) / 1024, 256, 0, stream>>>(X, Xb, MM * D_EMB);
  transpose_cast_all<<<dim3(24, 24, 4), tb, 0, stream>>>(Wq, Wk, Wv, Wo, WTqkv, WoT,
                                                         0.125f * 1.4426950408889634f);
  gemm_bt<0><<<dim3(E3 / 128, MM / 128), 256, 0, stream>>>(Xb, WTqkv, (void*)QKV,
                                                           MM, E3, D_EMB, 1.0f);
  transpose_v<<<dim3(SS / 32, 2, NB * NH), tb, 0, stream>>>(QKV, VT);
  flash<<<dim3(SS / 128, NH, NB), 256, 0, stream>>>(QKV, VT, Ob);
  gemm_bt<1><<<dim3(D_EMB / 128, MM / 128), 256, 0, stream>>>(Ob, WoT, (void*)out,
                                                              MM, D_EMB, D_EMB, 1.0f);
}